// Round 23
// baseline (146.001 us; speedup 1.0000x reference)
//
#include <hip/hip_runtime.h>

// Problem constants
#define NB    2048   // n_back (k)
#define NOUT  2048
#define NDIM  2048

// Output flat offsets (floats) in d_out: [w_u_, b_u_, w_l_, b_l_]
#define OFF_BU  16777216ull
#define OFF_WL  16785408ull
#define OFF_BL  33562624ull

// ws layout: [0,16384) floats bias partials (2,4,2048); then fragA (ushort[1536])
#define WS_T    16384

#define OP 104   // LDS o-stride in bf16 units ([nt][n][OP]); %8==0 for b128 align

typedef float f32x4  __attribute__((ext_vector_type(4)));
typedef short bf16x8 __attribute__((ext_vector_type(8)));

__device__ __host__ __forceinline__ unsigned short f2bf(float x) {
    union { float f; unsigned u; } v; v.f = x;
    unsigned r = v.u + 0x7FFFu + ((v.u >> 16) & 1u);   // RNE
    return (unsigned short)(r >> 16);
}

// HW packed convert: 2 f32 -> u32 holding 2 bf16 (lo = a, hi = b). RNE.
// No builtin on gfx950 — inline asm (guide T12 recipe).
__device__ __forceinline__ unsigned cvt2(float a, float b) {
    unsigned r;
    asm("v_cvt_pk_bf16_f32 %0, %1, %2" : "=v"(r) : "v"(a), "v"(b));
    return r;
}

// A-fragment prep: Amat[16 m][96 K] -> per-lane fragments, SAME slot->K-row
// map as the B-side LDS reads (slot j of lane-group g covers K-row
// kb*32 + g*8 + j). m = jw*8+ci; K-row = (s*4+w4)*8+co; weight =
// kern[kh=2-s][kw=2+jw-w4][ci][co], zero if kw out of range (k-permutation
// inside one MFMA is harmless as long as A and B agree — k is contracted).
__global__ void prep_kernel(const float* __restrict__ kern,
                            unsigned short* __restrict__ fragA) {
    const int i = blockIdx.x * 64 + threadIdx.x;   // 0..1535
    if (i < 1536) {
        const int kb = i >> 9, l = (i >> 3) & 63, j = i & 7;
        const int m = l & 15, g = l >> 4;
        const int kin = g * 8 + j;          // K-row within the 32-block
        const int w4 = kin >> 3, co = kin & 7;
        const int s  = kb;                  // K-blocks are s-aligned (32 = 4w4*8co)
        const int jw = m >> 3, ci = m & 7;
        const int kw = 2 + jw - w4;
        const int kh = 2 - s;
        float val = (kw >= 0 && kw <= 2)
            ? kern[((kh * 3 + kw) * 8 + ci) * 8 + co] : 0.f;
        fragA[i] = f2bf(val);
    }
}

// MFMA conv-backward (r22 structure, PROVEN correct; only change: the
// f32->bf16 conversion uses v_cvt_pk_bf16_f32 — r22 spent ~620 VALU
// ops/thread on software f2bf+packing, ~35us of the 168us dispatch).
__global__ __launch_bounds__(256) void conv_mfma_kernel(
    const float* __restrict__ wu,
    const float* __restrict__ wl,
    const unsigned short* __restrict__ fragA,
    const float* __restrict__ bias,
    float* __restrict__ outbuf,
    float* __restrict__ bias_ws)
{
    __shared__ unsigned short BL[16 * 16 * OP];   // [nt][n][o-swz]

    const int bid = blockIdx.x;        // 0..8191
    const int c   = bid & 7;           // k-chunk -> XCD (k-disjoint)
    const int j   = bid >> 3;
    const int p   = j & 7;             // wi pair (w0 = 2p)
    const int r   = (j >> 3) & 15;     // out row
    const int sl  = j >> 7;            // 0..7
    const int t = sl >> 2, b = sl & 3;
    const int tid = threadIdx.x;
    const int n   = tid & 15;
    const int z   = tid >> 4;          // 0..15 == nt this thread stages
    const int w   = tid >> 6;          // wave
    const int l   = tid & 63;

    const float* __restrict__ in = (t ? wl : wu) + (size_t)b * NOUT * NB;
    const int kbase = c * 256 + z * 16 + n;        // this thread's k column
    const int zx = (z & 3) << 3;                   // write-side o swizzle
    const int rowbase = (z * 16 + n) * OP;

    // ---- staging: 96 o-rows x (one k col/thread), f32 -> bf16 LDS ----
    float pb = 0.f;
    for (int it = 0; it < 24; ++it) {
        float vv[4];
        #pragma unroll
        for (int m = 0; m < 4; ++m) {
            const int o  = it * 4 + m;             // block-uniform row id
            const int s  = o >> 5, w4 = (o >> 3) & 3, co = o & 7;
            const int ho = r - 1 + s, wo = 2 * p - 1 + w4;
            float v = 0.f;
            if (((unsigned)ho < 16u) && ((unsigned)wo < 16u))   // scalar branch
                v = in[(size_t)((ho * 16 + wo) * 8 + co) * NB + kbase];
            if (o >= 40 && o < 56) pb += bias[co] * v;  // owned rows: s==1,w4 in {1,2}
            vv[m] = v;
        }
        uint2 pk2;
        pk2.x = cvt2(vv[0], vv[1]);    // bf16(vv0) | bf16(vv1)<<16
        pk2.y = cvt2(vv[2], vv[3]);
        *(uint2*)&BL[rowbase + ((it * 4) ^ zx)] = pk2;
    }

    // one f32 atomic per thread (per-k-column), 128 adds/address kernel-wide
    atomicAdd(&bias_ws[t * 8192 + b * 2048 + kbase], pb);

    __syncthreads();

    // ---- MFMA phase: wave w handles nt = w*4 .. w*4+3 ----
    const bf16x8 a0 = *(const bf16x8*)(fragA + 0 * 512 + l * 8);
    const bf16x8 a1 = *(const bf16x8*)(fragA + 1 * 512 + l * 8);
    const bf16x8 a2 = *(const bf16x8*)(fragA + 2 * 512 + l * 8);

    float* __restrict__ outp = outbuf + (t ? OFF_WL : 0) + (size_t)b * NDIM * NB;
    const int g = l >> 4;

    #pragma unroll
    for (int nt4 = 0; nt4 < 4; ++nt4) {
        const int nt = w * 4 + nt4;
        const int gs = ((g ^ (nt & 3)) * 8);       // un-swizzle reader side
        const unsigned short* base = &BL[(nt * 16 + (l & 15)) * OP + gs];
        const bf16x8 b0 = *(const bf16x8*)(base);        // kb=0: K-rows  0..31
        const bf16x8 b1 = *(const bf16x8*)(base + 32);   // kb=1: K-rows 32..63
        const bf16x8 b2 = *(const bf16x8*)(base + 64);   // kb=2: K-rows 64..95
        f32x4 acc = (f32x4)(0.f);
        acc = __builtin_amdgcn_mfma_f32_16x16x32_bf16(a0, b0, acc, 0, 0, 0);
        acc = __builtin_amdgcn_mfma_f32_16x16x32_bf16(a1, b1, acc, 0, 0, 0);
        acc = __builtin_amdgcn_mfma_f32_16x16x32_bf16(a2, b2, acc, 0, 0, 0);
        const int kcol = c * 256 + nt * 16 + (l & 15);
        #pragma unroll
        for (int q = 0; q < 4; ++q) {
            const int m = g * 4 + q;               // C/D: row=(l>>4)*4+reg (m89)
            const int i = (r * 16 + 2 * p + (m >> 3)) * 8 + (m & 7);
            outp[(size_t)i * NB + kcol] = acc[q];
        }
    }
}

// b_out_ = b_in + ws ; 16384 outputs (2 ul * 4 b * 2048 k)
__global__ void bias_finalize(const float* __restrict__ bu,
                              const float* __restrict__ bl,
                              const float* __restrict__ ws,
                              float* __restrict__ out)
{
    const int idx = blockIdx.x * blockDim.x + threadIdx.x;   // 0..16383
    const int ul  = idx >> 13;
    const int r   = idx & 8191;                              // b*2048 + k
    const float* bin = ul ? bl : bu;
    const size_t off = ul ? OFF_BL : OFF_BU;
    out[off + r] = bin[r] + ws[(size_t)ul * 8192 + r];
}

extern "C" void kernel_launch(void* const* d_in, const int* in_sizes, int n_in,
                              void* d_out, int out_size, void* d_ws, size_t ws_size,
                              hipStream_t stream) {
    // inputs: 0=x (unused), 1=kernel, 2=bias, 3=w_out_u, 4=b_out_u, 5=w_out_l, 6=b_out_l
    const float* kern = (const float*)d_in[1];
    const float* bias = (const float*)d_in[2];
    const float* wu   = (const float*)d_in[3];
    const float* bu   = (const float*)d_in[4];
    const float* wl   = (const float*)d_in[5];
    const float* bl   = (const float*)d_in[6];
    float* out = (float*)d_out;
    float* ws  = (float*)d_ws;

    // zero the 64 KB bias-partial region (graph replays re-run this node)
    (void)hipMemsetAsync(ws, 0, 2ull * 4 * NB * sizeof(float), stream);

    prep_kernel<<<24, 64, 0, stream>>>(kern, (unsigned short*)(ws + WS_T));
    conv_mfma_kernel<<<dim3(8192), dim3(256), 0, stream>>>(
        wu, wl, (const unsigned short*)(ws + WS_T), bias, out, ws);
    bias_finalize<<<64, 256, 0, stream>>>(bu, bl, ws, out);
}

// Round 24
// 81.116 us; speedup vs baseline: 1.7999x; 1.7999x over previous
//
#include <hip/hip_runtime.h>

// Problem constants
#define NB    2048   // n_back (k)
#define NB4   512    // NB/4 in f32x4 units
#define NOUT  2048   // H*W*COUT
#define NDIM  2048   // H*W*CIN

// Output flat offsets (floats) in d_out: [w_u_, b_u_, w_l_, b_l_]
#define OFF_BU  16777216ull
#define OFF_WL  16785408ull
#define OFF_BL  33562624ull

// ws layout (floats): [0,16384) bias partials (2,4,2048); [16384,+576) T
#define WS_T    16384

typedef float f32x2 __attribute__((ext_vector_type(2)));
typedef float f32x4 __attribute__((ext_vector_type(4)));

// T[co*72 + ci*9 + kh*3 + kw] = kern[((kh*3+kw)*8+ci)*8+co]
// -> per co, 72 CONTIGUOUS floats; block-uniform address -> s_load batches
// into the scalar file (round-10 mechanism; round-14: any threadIdx
// dependence here demotes weights to VMEM and destroys the kernel).
__global__ void prep_kernel(const float* __restrict__ kern, float* __restrict__ T) {
    const int i = blockIdx.x * 64 + threadIdx.x;   // 0..575
    if (i < 576) {
        const int kw = i % 3, kh = (i / 3) % 3, ci = (i / 9) % 8, co = i / 72;
        T[i] = kern[((kh * 3 + kw) * 8 + ci) * 8 + co];
    }
}

// FINAL (r19, best of session: 80.4us total, VGPR 44, traffic at floor).
// Structure: 1 owned out-row/thread, f32x4 over k, batch-9 loads per
// co-iteration, weights in SGPRs via block-uniform Tw addressing,
// k-disjoint XCD partition (bid&7 = k-chunk), LDS 4:1 bias reduction.
// Session lessons baked in:
//  - r9/r12/r18: VGPR caps convert live-set to scratch spills, never
//    shrink it (watch WRITE_SIZE for the spill signature).
//  - r10: wave-uniform weights belong in the scalar file; r14: they must
//    be BLOCK-uniform-addressed to stay there.
//  - r19: f32x2 source form does not produce v_pk_fma_f32 (neutral).
//  - r20: co-phase rotation neutral; r21: pinned dbuf loses to the VGPR
//    cost; r22/23: MFMA reformulation is staging-bound (168-184us).
__global__ __launch_bounds__(256, 3) void conv_back_kernel(
    const float* __restrict__ wu,
    const float* __restrict__ wl,
    const float* __restrict__ Tw,     // (8co, 72) transposed weights
    const float* __restrict__ bias,   // (8)
    float* __restrict__ outbuf,       // full d_out base
    float* __restrict__ bias_ws)      // (2,4,2048) partial bias sums
{
    const int bid = blockIdx.x;            // 0..4095
    const int klo = bid & 7;               // XCD id = k-chunk (k-disjoint)
    const int j   = bid >> 3;              // per-XCD order, 0..511
    const int r   = j & 15;                // owned out row (fastest: halo loc.)
    const int wig = (j >> 4) & 3;          // wi group
    const int sl  = j >> 6;                // 0..7 (t,b)
    const int t = sl >> 2, b = sl & 3;
    const int kl  = threadIdx.x & 63;
    const int sub = threadIdx.x >> 6;      // 0..3
    const int wi  = wig * 4 + sub;         // 0..15, wave-uniform
    const int k4  = klo * 64 + kl;         // f32x4 index over k, 0..511

    const f32x4* __restrict__ in =
        (const f32x4*)(t ? wl : wu) + (size_t)b * NOUT * NB4 + k4;
    f32x4* __restrict__ wout =
        (f32x4*)(outbuf + (t ? OFF_WL : 0)) + (size_t)b * NDIM * NB4 + k4;

    const bool vlo = wi > 0;               // wave-uniform edge masks
    const bool vhi = wi < 15;

    // block-uniform row validity (s: in-row r-1+s, s=0..2)
    bool rv[3];
    rv[0] = (r > 0);
    rv[1] = true;
    rv[2] = (r < 15);

    f32x2 acc[8][2];                       // [ci][k-half]
    #pragma unroll
    for (int ci = 0; ci < 8; ++ci) { acc[ci][0] = (f32x2)(0.f); acc[ci][1] = (f32x2)(0.f); }
    f32x4 pb = (f32x4)(0.f);

    #pragma unroll 1
    for (int co = 0; co < 8; ++co) {
        const float* __restrict__ tb = Tw + co * 72;  // block-uniform -> SGPR
        const float bco = bias[co];

        // ---- batched load phase: 9 loads in flight ----
        f32x4 u[3][3];                      // [s][wi-1, wi, wi+1]
        #pragma unroll
        for (int s = 0; s < 3; ++s) {
            if (rv[s]) {                    // block-uniform branch
                const int ho = r - 1 + s;
                const size_t base = (size_t)((ho * 16 + wi) * 8 + co) * NB4;
                u[s][0] = vlo ? in[base - 8 * NB4] : (f32x4)(0.f);
                u[s][1] =       in[base];
                u[s][2] = vhi ? in[base + 8 * NB4] : (f32x4)(0.f);
            } else {
                u[s][0] = (f32x4)(0.f);
                u[s][1] = (f32x4)(0.f);
                u[s][2] = (f32x4)(0.f);
            }
        }

        // owned row center column (in-row ho == r is s=1)
        pb += bco * u[1][1];

        // ---- FMA phase ----
        // in-row ho = r-1+s feeds out row r with kh = 2-s (r7-verified map)
        #pragma unroll
        for (int s = 0; s < 3; ++s) {
            const int kh = 2 - s;
            #pragma unroll
            for (int ci = 0; ci < 8; ++ci)
                #pragma unroll
                for (int kw = 0; kw < 3; ++kw) {
                    const float Kv = tb[ci * 9 + kh * 3 + kw];  // SGPR
                    const f32x2 kv2 = (f32x2)(Kv);              // splat
                    acc[ci][0] += kv2 * u[s][2 - kw].xy;        // dw = 1-kw
                    acc[ci][1] += kv2 * u[s][2 - kw].zw;
                }
        }
    }

    #pragma unroll
    for (int ci = 0; ci < 8; ++ci) {
        f32x4 o;
        o.xy = acc[ci][0];
        o.zw = acc[ci][1];
        wout[(size_t)((r * 16 + wi) * 8 + ci) * NB4] = o;
    }

    // reduce bias partials across the 4 sub-waves (same k4, different wi)
    __shared__ f32x4 red[4][64];
    red[sub][kl] = pb;
    __syncthreads();
    if (sub == 0) {
        f32x4 tot = red[0][kl] + red[1][kl] + red[2][kl] + red[3][kl];
        float* bws = bias_ws + t * 8192 + b * 2048 + 4 * k4;
        atomicAdd(bws + 0, tot.x);
        atomicAdd(bws + 1, tot.y);
        atomicAdd(bws + 2, tot.z);
        atomicAdd(bws + 3, tot.w);
    }
}

// b_out_ = b_in + ws ; 16384 outputs (2 ul * 4 b * 2048 k)
__global__ void bias_finalize(const float* __restrict__ bu,
                              const float* __restrict__ bl,
                              const float* __restrict__ ws,
                              float* __restrict__ out)
{
    const int idx = blockIdx.x * blockDim.x + threadIdx.x;   // 0..16383
    const int ul  = idx >> 13;
    const int r   = idx & 8191;                              // b*2048 + k
    const float* bin = ul ? bl : bu;
    const size_t off = ul ? OFF_BL : OFF_BU;
    out[off + r] = bin[r] + ws[(size_t)ul * 8192 + r];
}

extern "C" void kernel_launch(void* const* d_in, const int* in_sizes, int n_in,
                              void* d_out, int out_size, void* d_ws, size_t ws_size,
                              hipStream_t stream) {
    // inputs: 0=x (unused), 1=kernel, 2=bias, 3=w_out_u, 4=b_out_u, 5=w_out_l, 6=b_out_l
    const float* kern = (const float*)d_in[1];
    const float* bias = (const float*)d_in[2];
    const float* wu   = (const float*)d_in[3];
    const float* bu   = (const float*)d_in[4];
    const float* wl   = (const float*)d_in[5];
    const float* bl   = (const float*)d_in[6];
    float* out = (float*)d_out;
    float* ws  = (float*)d_ws;

    // zero the 64 KB bias-partial region (graph replays re-run this node)
    (void)hipMemsetAsync(ws, 0, 2ull * 4 * NB * sizeof(float), stream);

    prep_kernel<<<9, 64, 0, stream>>>(kern, ws + WS_T);
    conv_back_kernel<<<dim3(4096), dim3(256), 0, stream>>>(wu, wl, ws + WS_T, bias, out, ws);
    bias_finalize<<<64, 256, 0, stream>>>(bu, bl, ws, out);
}